// Round 1
// baseline (112.881 us; speedup 1.0000x reference)
//
#include <hip/hip_runtime.h>
#include <math.h>

// CompressedAttention: B=4,S=4096,H=2,KVH=1,D=2,MD=5
// Algebraic collapse: scores_ij = alpha_{h,i}*P_j + beta_{h,i}*Q_j (rank-2),
// v colinear -> out weight is a scalar per (row,head). O(S^2) cheap ops, no GEMM.

#define BQ 4
#define SQ 4096
#define MDQ 5
#define EPSQ 1e-6f
#define SCALEQ 16.0f

#define BLOCK 256
#define ROWS 32            // rows (query positions) per block
#define SPLIT 8            // threads cooperating per row (j-split)
#define JSUB (SQ / SPLIT)  // 512 keys per thread
#define TILES (SQ / ROWS)  // 128 row-tiles per batch

__global__ __launch_bounds__(BLOCK)
void ca_kernel(const float* __restrict__ x,
               const float* __restrict__ freqs,
               const float* __restrict__ qk_v,
               const float* __restrict__ v_v,
               const float* __restrict__ o_v,
               const float* __restrict__ vproj_u,
               const float* __restrict__ q_u,
               const float* __restrict__ k_u,
               const float* __restrict__ o_u,
               float* __restrict__ out)
{
    __shared__ float2 sPQ[SQ];                    // 32 KB: (P_j, Q_j)
    __shared__ float  sCv[SQ];                    // 16 KB: sv_j
    __shared__ float  sRed[ROWS][SPLIT][2][3];    // 6 KB: per-(row,split,head) m,l,num

    const int tid  = threadIdx.x;
    const int bx   = blockIdx.x;
    const int b    = bx / TILES;
    const int tile = bx % TILES;

    // ---- tiny parameter vectors (L1-cached, read redundantly) ----
    const float w0 = k_u[0], w1 = k_u[1];
    const float mk = 0.5f * (w0 * w0 + w1 * w1);

    const float qk0 = qk_v[0], qk1 = qk_v[1], qk2 = qk_v[2], qk3 = qk_v[3], qk4 = qk_v[4];
    const float vv0 = v_v[0],  vv1 = v_v[1],  vv2 = v_v[2],  vv3 = v_v[3],  vv4 = v_v[4];

    // ---- stage per-key scalars P,Q,Cv for batch b into LDS ----
    for (int k = 0; k < SQ / BLOCK; ++k) {
        const int j = tid + k * BLOCK;
        const float* xr = x + (size_t)(b * SQ + j) * MDQ;
        const float x0 = xr[0], x1 = xr[1], x2 = xr[2], x3 = xr[3], x4 = xr[4];
        const float a  = x0*qk0 + x1*qk1 + x2*qk2 + x3*qk3 + x4*qk4;
        const float sv = x0*vv0 + x1*vv1 + x2*vv2 + x3*vv3 + x4*vv4;
        float sj, cj;
        __sincosf(freqs[j], &sj, &cj);
        const float mu = SCALEQ * a * rsqrtf(a * a * mk + EPSQ);  // rmsnorm(k) scalar
        sPQ[j] = make_float2(mu * cj, mu * sj);
        sCv[j] = sv;
    }

    // ---- per-row query setup ----
    const int row = tid & (ROWS - 1);
    const int sp  = tid / ROWS;          // 0..7
    const int i   = tile * ROWS + row;

    const float u00 = q_u[0], u01 = q_u[1], u10 = q_u[2], u11 = q_u[3];
    const float m0 = 0.5f * (u00 * u00 + u01 * u01);
    const float m1 = 0.5f * (u10 * u10 + u11 * u11);
    const float A0 = u00 * w0 + u01 * w1, B0 = u01 * w0 - u00 * w1;
    const float A1 = u10 * w0 + u11 * w1, B1 = u11 * w0 - u10 * w1;

    const float* xi = x + (size_t)(b * SQ + i) * MDQ;
    const float ai = xi[0]*qk0 + xi[1]*qk1 + xi[2]*qk2 + xi[3]*qk3 + xi[4]*qk4;
    float si, ci;
    __sincosf(freqs[i], &si, &ci);
    const float lam0 = SCALEQ * ai * rsqrtf(ai * ai * m0 + EPSQ);
    const float lam1 = SCALEQ * ai * rsqrtf(ai * ai * m1 + EPSQ);
    const float isq2 = 0.70710678118654752f;   // 1/sqrt(D), D=2
    const float al0 = lam0 * (A0 * ci - B0 * si) * isq2;
    const float be0 = lam0 * (A0 * si + B0 * ci) * isq2;
    const float al1 = lam1 * (A1 * ci - B1 * si) * isq2;
    const float be1 = lam1 * (A1 * si + B1 * ci) * isq2;

    __syncthreads();

    // ---- pass 1: exact max over this thread's key chunk ----
    const float2* __restrict__ pq  = sPQ + sp * JSUB;
    const float*  __restrict__ cvp = sCv + sp * JSUB;

    float mx0 = -1e30f, mx1 = -1e30f;
#pragma unroll 8
    for (int jj = 0; jj < JSUB; ++jj) {
        const float2 v = pq[jj];
        const float sc0 = al0 * v.x + be0 * v.y;
        const float sc1 = al1 * v.x + be1 * v.y;
        mx0 = fmaxf(mx0, sc0);
        mx1 = fmaxf(mx1, sc1);
    }

    // ---- pass 2: exp-sum (l) and value-weighted sum (num) ----
    float l0 = 0.f, n0 = 0.f, l1 = 0.f, n1 = 0.f;
#pragma unroll 4
    for (int jj = 0; jj < JSUB; ++jj) {
        const float2 v = pq[jj];
        const float cv = cvp[jj];
        const float e0 = __expf(al0 * v.x + be0 * v.y - mx0);
        const float e1 = __expf(al1 * v.x + be1 * v.y - mx1);
        l0 += e0; n0 = fmaf(e0, cv, n0);
        l1 += e1; n1 = fmaf(e1, cv, n1);
    }

    sRed[row][sp][0][0] = mx0; sRed[row][sp][0][1] = l0; sRed[row][sp][0][2] = n0;
    sRed[row][sp][1][0] = mx1; sRed[row][sp][1][1] = l1; sRed[row][sp][1][2] = n1;
    __syncthreads();

    // ---- combine splits + epilogue (one thread per row) ----
    if (tid < ROWS) {
        float W[2];
#pragma unroll
        for (int h = 0; h < 2; ++h) {
            float m = -1e30f;
#pragma unroll
            for (int s = 0; s < SPLIT; ++s) m = fmaxf(m, sRed[tid][s][h][0]);
            float l = 0.f, n = 0.f;
#pragma unroll
            for (int s = 0; s < SPLIT; ++s) {
                const float c = __expf(sRed[tid][s][h][0] - m);
                l = fmaf(sRed[tid][s][h][1], c, l);
                n = fmaf(sRed[tid][s][h][2], c, n);
            }
            W[h] = n / l;
        }
        const float p0 = vproj_u[0], p1 = vproj_u[1];
        const float d0 = p0 * o_v[0] + p1 * o_v[1];
        const float d1 = p0 * o_v[2] + p1 * o_v[3];
        const float so = W[0] * d0 + W[1] * d1;

        const int ig = tile * ROWS + tid;
        float* orow = out + (size_t)(b * SQ + ig) * MDQ;
        orow[0] = so * o_u[0];
        orow[1] = so * o_u[1];
        orow[2] = so * o_u[2];
        orow[3] = so * o_u[3];
        orow[4] = so * o_u[4];
    }
}

extern "C" void kernel_launch(void* const* d_in, const int* in_sizes, int n_in,
                              void* d_out, int out_size, void* d_ws, size_t ws_size,
                              hipStream_t stream) {
    (void)in_sizes; (void)n_in; (void)d_ws; (void)ws_size; (void)out_size;
    const float* x       = (const float*)d_in[0];
    const float* freqs   = (const float*)d_in[1];
    const float* qk_v    = (const float*)d_in[2];
    const float* v_v     = (const float*)d_in[3];
    const float* o_v     = (const float*)d_in[4];
    const float* vproj_u = (const float*)d_in[5];
    const float* q_u     = (const float*)d_in[6];
    const float* k_u     = (const float*)d_in[7];
    const float* o_u     = (const float*)d_in[8];
    float* out = (float*)d_out;

    dim3 grid(BQ * TILES);   // 512 blocks
    dim3 block(BLOCK);
    hipLaunchKernelGGL(ca_kernel, grid, block, 0, stream,
                       x, freqs, qk_v, v_v, o_v, vproj_u, q_u, k_u, o_u, out);
}

// Round 2
// 107.718 us; speedup vs baseline: 1.0479x; 1.0479x over previous
//
#include <hip/hip_runtime.h>
#include <math.h>

// CompressedAttention: B=4,S=4096,H=2,KVH=1,D=2,MD=5
// Algebraic collapse: scores_ij = al_{h,i}*P_j + be_{h,i}*Q_j (rank-2),
// v colinear -> out weight is a scalar per (row,head).
// R2: single-pass softmax via analytic shift M = r*Mmu (|score| <= M exactly),
// key scalars (P,Q,Cv) precomputed once to global (L2-resident), LDS only 4KB.

#define BQ 4
#define SQ 4096
#define MDQ 5
#define EPSQ 1e-6f
#define SCALEQ 16.0f
#define L2E 1.4426950408889634f
#define ISQ2 0.70710678118654752f

__device__ __forceinline__ float fast_exp2(float x) {
#if __has_builtin(__builtin_amdgcn_exp2f)
    return __builtin_amdgcn_exp2f(x);
#else
    return __expf(x * 0.6931471805599453f);
#endif
}

// ---------------- pre-pass: per-key scalars (P,Q,Cv) ----------------
__global__ __launch_bounds__(256)
void ca_prep(const float* __restrict__ x, const float* __restrict__ freqs,
             const float* __restrict__ qk_v, const float* __restrict__ v_v,
             const float* __restrict__ k_u, float4* __restrict__ pqc)
{
    const int idx = blockIdx.x * 256 + threadIdx.x;   // 0 .. B*S-1
    const int j   = idx & (SQ - 1);

    const float w0 = k_u[0], w1 = k_u[1];
    const float mk = 0.5f * (w0 * w0 + w1 * w1);

    const float qk0 = qk_v[0], qk1 = qk_v[1], qk2 = qk_v[2], qk3 = qk_v[3], qk4 = qk_v[4];
    const float vv0 = v_v[0],  vv1 = v_v[1],  vv2 = v_v[2],  vv3 = v_v[3],  vv4 = v_v[4];

    const float* xr = x + (size_t)idx * MDQ;
    const float x0 = xr[0], x1 = xr[1], x2 = xr[2], x3 = xr[3], x4 = xr[4];
    const float a  = x0*qk0 + x1*qk1 + x2*qk2 + x3*qk3 + x4*qk4;
    const float sv = x0*vv0 + x1*vv1 + x2*vv2 + x3*vv3 + x4*vv4;

    float sj, cj;
    __sincosf(freqs[j], &sj, &cj);
    const float mu = SCALEQ * a * rsqrtf(a * a * mk + EPSQ);   // rmsnorm(k) scalar
    pqc[idx] = make_float4(mu * cj, mu * sj, sv, 0.0f);
}

// ---------------- main kernel (global PQC path) ----------------
#define BLOCK 256
#define ROWS 16            // query rows per block
#define SPLIT 16           // threads per row (j-split)
#define JSUB (SQ / SPLIT)  // 256 keys per thread
#define TILES (SQ / ROWS)  // 256 row-tiles per batch

__global__ __launch_bounds__(BLOCK)
void ca_main(const float* __restrict__ x,
             const float* __restrict__ freqs,
             const float* __restrict__ qk_v,
             const float* __restrict__ o_v,
             const float* __restrict__ vproj_u,
             const float* __restrict__ q_u,
             const float* __restrict__ k_u,
             const float* __restrict__ o_u,
             const float4* __restrict__ pqc,
             float* __restrict__ out)
{
    __shared__ float4 sRed[ROWS][SPLIT];    // 4 KB: per-(row,split) l0,n0,l1,n1

    const int tid  = threadIdx.x;
    const int bx   = blockIdx.x;
    const int b    = bx / TILES;
    const int tile = bx % TILES;
    const int row  = tid & (ROWS - 1);
    const int sp   = tid / ROWS;
    const int i    = tile * ROWS + row;

    // ---- per-row coefficients (redundant across sp; tiny) ----
    const float w0 = k_u[0], w1 = k_u[1];
    const float mk  = 0.5f * (w0 * w0 + w1 * w1);
    const float Mmu = SCALEQ * rsqrtf(mk);            // bound on |mu_j|

    const float qk0 = qk_v[0], qk1 = qk_v[1], qk2 = qk_v[2], qk3 = qk_v[3], qk4 = qk_v[4];
    const float u00 = q_u[0], u01 = q_u[1], u10 = q_u[2], u11 = q_u[3];
    const float m0 = 0.5f * (u00 * u00 + u01 * u01);
    const float m1 = 0.5f * (u10 * u10 + u11 * u11);
    const float A0 = u00 * w0 + u01 * w1, B0 = u01 * w0 - u00 * w1;
    const float A1 = u10 * w0 + u11 * w1, B1 = u11 * w0 - u10 * w1;

    const float* xi = x + (size_t)(b * SQ + i) * MDQ;
    const float ai = xi[0]*qk0 + xi[1]*qk1 + xi[2]*qk2 + xi[3]*qk3 + xi[4]*qk4;
    float si, ci;
    __sincosf(freqs[i], &si, &ci);
    const float lam0 = SCALEQ * ai * rsqrtf(ai * ai * m0 + EPSQ);
    const float lam1 = SCALEQ * ai * rsqrtf(ai * ai * m1 + EPSQ);

    const float alr0 = lam0 * (A0 * ci - B0 * si) * ISQ2;
    const float ber0 = lam0 * (A0 * si + B0 * ci) * ISQ2;
    const float alr1 = lam1 * (A1 * ci - B1 * si) * ISQ2;
    const float ber1 = lam1 * (A1 * si + B1 * ci) * ISQ2;
    const float r0 = sqrtf(alr0 * alr0 + ber0 * ber0);
    const float r1 = sqrtf(alr1 * alr1 + ber1 * ber1);

    // fold log2e and the shift -r*Mmu into the score coefficients
    const float al0 = alr0 * L2E, be0 = ber0 * L2E, C0 = -r0 * Mmu * L2E;
    const float al1 = alr1 * L2E, be1 = ber1 * L2E, C1 = -r1 * Mmu * L2E;

    // ---- single pass over this thread's key chunk ----
    const float4* __restrict__ p = pqc + (size_t)b * SQ + sp * JSUB;
    float l0 = 0.f, n0 = 0.f, l1 = 0.f, n1 = 0.f;
#pragma unroll 8
    for (int jj = 0; jj < JSUB; ++jj) {
        const float4 v = p[jj];
        const float s0 = fmaf(al0, v.x, fmaf(be0, v.y, C0));
        const float s1 = fmaf(al1, v.x, fmaf(be1, v.y, C1));
        const float e0 = fast_exp2(s0);
        const float e1 = fast_exp2(s1);
        l0 += e0; n0 = fmaf(e0, v.z, n0);
        l1 += e1; n1 = fmaf(e1, v.z, n1);
    }

    sRed[row][sp] = make_float4(l0, n0, l1, n1);
    __syncthreads();

    // ---- combine splits + epilogue (one thread per row) ----
    if (tid < ROWS) {
        float L0 = 0.f, N0 = 0.f, L1 = 0.f, N1 = 0.f;
#pragma unroll
        for (int s = 0; s < SPLIT; ++s) {
            const float4 t = sRed[tid][s];
            L0 += t.x; N0 += t.y; L1 += t.z; N1 += t.w;
        }
        L0 = fmaxf(L0, 1e-30f);
        L1 = fmaxf(L1, 1e-30f);
        const float W0 = N0 / L0, W1 = N1 / L1;

        const float p0 = vproj_u[0], p1 = vproj_u[1];
        const float d0 = p0 * o_v[0] + p1 * o_v[1];
        const float d1 = p0 * o_v[2] + p1 * o_v[3];
        const float so = W0 * d0 + W1 * d1;

        const int ig = tile * ROWS + tid;
        float* orow = out + (size_t)(b * SQ + ig) * MDQ;
        orow[0] = so * o_u[0];
        orow[1] = so * o_u[1];
        orow[2] = so * o_u[2];
        orow[3] = so * o_u[3];
        orow[4] = so * o_u[4];
    }
}

// ---------------- fallback: single kernel, LDS-staged keys ----------------
#define FROWS 32
#define FSPLIT 8
#define FJSUB (SQ / FSPLIT)
#define FTILES (SQ / FROWS)

__global__ __launch_bounds__(256)
void ca_fallback(const float* __restrict__ x,
                 const float* __restrict__ freqs,
                 const float* __restrict__ qk_v,
                 const float* __restrict__ v_v,
                 const float* __restrict__ o_v,
                 const float* __restrict__ vproj_u,
                 const float* __restrict__ q_u,
                 const float* __restrict__ k_u,
                 const float* __restrict__ o_u,
                 float* __restrict__ out)
{
    __shared__ float2 sPQ[SQ];                 // 32 KB
    __shared__ float  sCv[SQ];                 // 16 KB
    __shared__ float4 sRed[FROWS][FSPLIT];     // 4 KB

    const int tid  = threadIdx.x;
    const int b    = blockIdx.x / FTILES;
    const int tile = blockIdx.x % FTILES;

    const float w0 = k_u[0], w1 = k_u[1];
    const float mk  = 0.5f * (w0 * w0 + w1 * w1);
    const float Mmu = SCALEQ * rsqrtf(mk);

    const float qk0 = qk_v[0], qk1 = qk_v[1], qk2 = qk_v[2], qk3 = qk_v[3], qk4 = qk_v[4];
    const float vv0 = v_v[0],  vv1 = v_v[1],  vv2 = v_v[2],  vv3 = v_v[3],  vv4 = v_v[4];

    for (int k = 0; k < SQ / 256; ++k) {
        const int j = tid + k * 256;
        const float* xr = x + (size_t)(b * SQ + j) * MDQ;
        const float x0 = xr[0], x1 = xr[1], x2 = xr[2], x3 = xr[3], x4 = xr[4];
        const float a  = x0*qk0 + x1*qk1 + x2*qk2 + x3*qk3 + x4*qk4;
        const float sv = x0*vv0 + x1*vv1 + x2*vv2 + x3*vv3 + x4*vv4;
        float sj, cj;
        __sincosf(freqs[j], &sj, &cj);
        const float mu = SCALEQ * a * rsqrtf(a * a * mk + EPSQ);
        sPQ[j] = make_float2(mu * cj, mu * sj);
        sCv[j] = sv;
    }

    const int row = tid & (FROWS - 1);
    const int sp  = tid / FROWS;
    const int i   = tile * FROWS + row;

    const float u00 = q_u[0], u01 = q_u[1], u10 = q_u[2], u11 = q_u[3];
    const float m0 = 0.5f * (u00 * u00 + u01 * u01);
    const float m1 = 0.5f * (u10 * u10 + u11 * u11);
    const float A0 = u00 * w0 + u01 * w1, B0 = u01 * w0 - u00 * w1;
    const float A1 = u10 * w0 + u11 * w1, B1 = u11 * w0 - u10 * w1;

    const float* xi = x + (size_t)(b * SQ + i) * MDQ;
    const float ai = xi[0]*qk0 + xi[1]*qk1 + xi[2]*qk2 + xi[3]*qk3 + xi[4]*qk4;
    float si, ci;
    __sincosf(freqs[i], &si, &ci);
    const float lam0 = SCALEQ * ai * rsqrtf(ai * ai * m0 + EPSQ);
    const float lam1 = SCALEQ * ai * rsqrtf(ai * ai * m1 + EPSQ);
    const float alr0 = lam0 * (A0 * ci - B0 * si) * ISQ2;
    const float ber0 = lam0 * (A0 * si + B0 * ci) * ISQ2;
    const float alr1 = lam1 * (A1 * ci - B1 * si) * ISQ2;
    const float ber1 = lam1 * (A1 * si + B1 * ci) * ISQ2;
    const float r0 = sqrtf(alr0 * alr0 + ber0 * ber0);
    const float r1 = sqrtf(alr1 * alr1 + ber1 * ber1);
    const float al0 = alr0 * L2E, be0 = ber0 * L2E, C0 = -r0 * Mmu * L2E;
    const float al1 = alr1 * L2E, be1 = ber1 * L2E, C1 = -r1 * Mmu * L2E;

    __syncthreads();

    const float2* __restrict__ pq  = sPQ + sp * FJSUB;
    const float*  __restrict__ cvp = sCv + sp * FJSUB;
    float l0 = 0.f, n0 = 0.f, l1 = 0.f, n1 = 0.f;
#pragma unroll 8
    for (int jj = 0; jj < FJSUB; ++jj) {
        const float2 v = pq[jj];
        const float cv = cvp[jj];
        const float s0 = fmaf(al0, v.x, fmaf(be0, v.y, C0));
        const float s1 = fmaf(al1, v.x, fmaf(be1, v.y, C1));
        const float e0 = fast_exp2(s0);
        const float e1 = fast_exp2(s1);
        l0 += e0; n0 = fmaf(e0, cv, n0);
        l1 += e1; n1 = fmaf(e1, cv, n1);
    }

    sRed[row][sp] = make_float4(l0, n0, l1, n1);
    __syncthreads();

    if (tid < FROWS) {
        float L0 = 0.f, N0 = 0.f, L1 = 0.f, N1 = 0.f;
#pragma unroll
        for (int s = 0; s < FSPLIT; ++s) {
            const float4 t = sRed[tid][s];
            L0 += t.x; N0 += t.y; L1 += t.z; N1 += t.w;
        }
        L0 = fmaxf(L0, 1e-30f);
        L1 = fmaxf(L1, 1e-30f);
        const float W0 = N0 / L0, W1 = N1 / L1;
        const float p0 = vproj_u[0], p1 = vproj_u[1];
        const float d0 = p0 * o_v[0] + p1 * o_v[1];
        const float d1 = p0 * o_v[2] + p1 * o_v[3];
        const float so = W0 * d0 + W1 * d1;

        const int ig = tile * FROWS + tid;
        float* orow = out + (size_t)(b * SQ + ig) * MDQ;
        orow[0] = so * o_u[0];
        orow[1] = so * o_u[1];
        orow[2] = so * o_u[2];
        orow[3] = so * o_u[3];
        orow[4] = so * o_u[4];
    }
}

extern "C" void kernel_launch(void* const* d_in, const int* in_sizes, int n_in,
                              void* d_out, int out_size, void* d_ws, size_t ws_size,
                              hipStream_t stream) {
    (void)in_sizes; (void)n_in; (void)out_size;
    const float* x       = (const float*)d_in[0];
    const float* freqs   = (const float*)d_in[1];
    const float* qk_v    = (const float*)d_in[2];
    const float* v_v     = (const float*)d_in[3];
    const float* o_v     = (const float*)d_in[4];
    const float* vproj_u = (const float*)d_in[5];
    const float* q_u     = (const float*)d_in[6];
    const float* k_u     = (const float*)d_in[7];
    const float* o_u     = (const float*)d_in[8];
    float* out = (float*)d_out;

    const size_t pqc_bytes = (size_t)BQ * SQ * sizeof(float4);   // 256 KB
    if (ws_size >= pqc_bytes) {
        float4* pqc = (float4*)d_ws;
        hipLaunchKernelGGL(ca_prep, dim3(BQ * SQ / 256), dim3(256), 0, stream,
                           x, freqs, qk_v, v_v, k_u, pqc);
        hipLaunchKernelGGL(ca_main, dim3(BQ * TILES), dim3(BLOCK), 0, stream,
                           x, freqs, qk_v, o_v, vproj_u, q_u, k_u, o_u, pqc, out);
    } else {
        hipLaunchKernelGGL(ca_fallback, dim3(BQ * FTILES), dim3(256), 0, stream,
                           x, freqs, qk_v, v_v, o_v, vproj_u, q_u, k_u, o_u, out);
    }
}

// Round 3
// 96.873 us; speedup vs baseline: 1.1652x; 1.1120x over previous
//
#include <hip/hip_runtime.h>
#include <math.h>

// CompressedAttention: B=4,S=4096,H=2,KVH=1,D=2,MD=5
// scores_ij = al_{h,i}*P_j + be_{h,i}*Q_j (rank-2); v colinear -> scalar out weight.
// R3: 4 rows/thread register blocking (1 float4 key-load feeds 8 score chains),
// wave-owned rows + shfl_xor butterfly reduction (zero LDS in main kernel),
// analytic softmax shift (single pass, no max scan).

#define BQ 4
#define SQ 4096
#define MDQ 5
#define EPSQ 1e-6f
#define SCALEQ 16.0f
#define L2E 1.4426950408889634f
#define ISQ2 0.70710678118654752f

__device__ __forceinline__ float fast_exp2(float x) {
#if __has_builtin(__builtin_amdgcn_exp2f)
    return __builtin_amdgcn_exp2f(x);
#else
    return __expf(x * 0.6931471805599453f);
#endif
}

// ---------------- pre-pass: per-key scalars (P,Q,Cv) ----------------
__global__ __launch_bounds__(256)
void ca_prep(const float* __restrict__ x, const float* __restrict__ freqs,
             const float* __restrict__ qk_v, const float* __restrict__ v_v,
             const float* __restrict__ k_u, float4* __restrict__ pqc)
{
    const int idx = blockIdx.x * 256 + threadIdx.x;   // 0 .. B*S-1
    const int j   = idx & (SQ - 1);

    const float w0 = k_u[0], w1 = k_u[1];
    const float mk = 0.5f * (w0 * w0 + w1 * w1);

    const float qk0 = qk_v[0], qk1 = qk_v[1], qk2 = qk_v[2], qk3 = qk_v[3], qk4 = qk_v[4];
    const float vv0 = v_v[0],  vv1 = v_v[1],  vv2 = v_v[2],  vv3 = v_v[3],  vv4 = v_v[4];

    const float* xr = x + (size_t)idx * MDQ;
    const float x0 = xr[0], x1 = xr[1], x2 = xr[2], x3 = xr[3], x4 = xr[4];
    const float a  = x0*qk0 + x1*qk1 + x2*qk2 + x3*qk3 + x4*qk4;
    const float sv = x0*vv0 + x1*vv1 + x2*vv2 + x3*vv3 + x4*vv4;

    float sj, cj;
    __sincosf(freqs[j], &sj, &cj);
    const float mu = SCALEQ * a * rsqrtf(a * a * mk + EPSQ);   // rmsnorm(k) scalar
    pqc[idx] = make_float4(mu * cj, mu * sj, sv, 0.0f);
}

// ---------------- main kernel ----------------
#define BLOCK 256
#define SPLIT 64            // one wave = 64 key-split lanes
#define RSETS 4             // waves per block
#define RPT 4               // rows per thread (register-blocked)
#define ROWSB (RSETS * RPT) // 16 rows per block
#define JITER (SQ / SPLIT)  // 64 key iterations per thread
#define TILES (SQ / ROWSB)  // 256 tiles per batch -> grid 1024

__global__ __launch_bounds__(BLOCK)
void ca_main(const float* __restrict__ x,
             const float* __restrict__ freqs,
             const float* __restrict__ qk_v,
             const float* __restrict__ o_v,
             const float* __restrict__ vproj_u,
             const float* __restrict__ q_u,
             const float* __restrict__ k_u,
             const float* __restrict__ o_u,
             const float4* __restrict__ pqc,
             float* __restrict__ out)
{
    const int tid = threadIdx.x;
    const int sp  = tid & 63;        // key-split lane within wave
    const int rs  = tid >> 6;        // wave index = row-set
    const int bx  = blockIdx.x;
    const int b   = bx / TILES;
    const int tile = bx % TILES;
    const int i0  = tile * ROWSB + rs * RPT;   // first row of this wave

    // ---- tiny shared params (broadcast loads) ----
    const float w0 = k_u[0], w1 = k_u[1];
    const float mk  = 0.5f * (w0 * w0 + w1 * w1);
    const float Mmu = SCALEQ * rsqrtf(mk);     // exact bound on |mu_j|

    const float qk0 = qk_v[0], qk1 = qk_v[1], qk2 = qk_v[2], qk3 = qk_v[3], qk4 = qk_v[4];
    const float u00 = q_u[0], u01 = q_u[1], u10 = q_u[2], u11 = q_u[3];
    const float m0 = 0.5f * (u00 * u00 + u01 * u01);
    const float m1 = 0.5f * (u10 * u10 + u11 * u11);
    const float A0 = u00 * w0 + u01 * w1, B0 = u01 * w0 - u00 * w1;
    const float A1 = u10 * w0 + u11 * w1, B1 = u11 * w0 - u10 * w1;

    // ---- per-row score coefficients (4 rows, registers) ----
    float al0[RPT], be0[RPT], C0[RPT], al1[RPT], be1[RPT], C1[RPT];
#pragma unroll
    for (int k = 0; k < RPT; ++k) {
        const int i = i0 + k;
        const float* xi = x + (size_t)(b * SQ + i) * MDQ;
        const float ai = xi[0]*qk0 + xi[1]*qk1 + xi[2]*qk2 + xi[3]*qk3 + xi[4]*qk4;
        float si, ci;
        __sincosf(freqs[i], &si, &ci);
        const float lam0 = SCALEQ * ai * rsqrtf(ai * ai * m0 + EPSQ);
        const float lam1 = SCALEQ * ai * rsqrtf(ai * ai * m1 + EPSQ);
        const float a0 = lam0 * (A0 * ci - B0 * si) * ISQ2;
        const float b0_ = lam0 * (A0 * si + B0 * ci) * ISQ2;
        const float a1 = lam1 * (A1 * ci - B1 * si) * ISQ2;
        const float b1_ = lam1 * (A1 * si + B1 * ci) * ISQ2;
        const float r0 = sqrtf(a0 * a0 + b0_ * b0_);
        const float r1 = sqrtf(a1 * a1 + b1_ * b1_);
        al0[k] = a0 * L2E;  be0[k] = b0_ * L2E;  C0[k] = -r0 * Mmu * L2E;
        al1[k] = a1 * L2E;  be1[k] = b1_ * L2E;  C1[k] = -r1 * Mmu * L2E;
    }

    // ---- single pass over keys: j = jj*64 + sp (coalesced 1KB/wave) ----
    const float4* __restrict__ p = pqc + (size_t)b * SQ + sp;
    float l0[RPT], n0[RPT], l1[RPT], n1[RPT];
#pragma unroll
    for (int k = 0; k < RPT; ++k) { l0[k] = 0.f; n0[k] = 0.f; l1[k] = 0.f; n1[k] = 0.f; }

#pragma unroll 4
    for (int jj = 0; jj < JITER; ++jj) {
        const float4 v = p[(size_t)jj * 64];
#pragma unroll
        for (int k = 0; k < RPT; ++k) {
            const float s0 = fmaf(al0[k], v.x, fmaf(be0[k], v.y, C0[k]));
            const float s1 = fmaf(al1[k], v.x, fmaf(be1[k], v.y, C1[k]));
            const float e0 = fast_exp2(s0);
            const float e1 = fast_exp2(s1);
            l0[k] += e0;  n0[k] = fmaf(e0, v.z, n0[k]);
            l1[k] += e1;  n1[k] = fmaf(e1, v.z, n1[k]);
        }
    }

    // ---- full-wave butterfly reduction (all 64 splits live in this wave) ----
#pragma unroll
    for (int m = 1; m < 64; m <<= 1) {
#pragma unroll
        for (int k = 0; k < RPT; ++k) {
            l0[k] += __shfl_xor(l0[k], m, 64);
            n0[k] += __shfl_xor(n0[k], m, 64);
            l1[k] += __shfl_xor(l1[k], m, 64);
            n1[k] += __shfl_xor(n1[k], m, 64);
        }
    }

    // ---- epilogue: lanes 0..3 each write one row ----
    if (sp < RPT) {
        const int k = sp;
        const float L0 = fmaxf(l0[k], 1e-30f);
        const float L1 = fmaxf(l1[k], 1e-30f);
        const float W0 = n0[k] / L0, W1 = n1[k] / L1;

        const float p0 = vproj_u[0], p1 = vproj_u[1];
        const float d0 = p0 * o_v[0] + p1 * o_v[1];
        const float d1 = p0 * o_v[2] + p1 * o_v[3];
        const float so = W0 * d0 + W1 * d1;

        float* orow = out + (size_t)(b * SQ + i0 + k) * MDQ;
        orow[0] = so * o_u[0];
        orow[1] = so * o_u[1];
        orow[2] = so * o_u[2];
        orow[3] = so * o_u[3];
        orow[4] = so * o_u[4];
    }
}

// ---------------- fallback: single kernel, LDS-staged keys ----------------
#define FROWS 32
#define FSPLIT 8
#define FJSUB (SQ / FSPLIT)
#define FTILES (SQ / FROWS)

__global__ __launch_bounds__(256)
void ca_fallback(const float* __restrict__ x,
                 const float* __restrict__ freqs,
                 const float* __restrict__ qk_v,
                 const float* __restrict__ v_v,
                 const float* __restrict__ o_v,
                 const float* __restrict__ vproj_u,
                 const float* __restrict__ q_u,
                 const float* __restrict__ k_u,
                 const float* __restrict__ o_u,
                 float* __restrict__ out)
{
    __shared__ float2 sPQ[SQ];
    __shared__ float  sCv[SQ];
    __shared__ float4 sRed[FROWS][FSPLIT];

    const int tid  = threadIdx.x;
    const int b    = blockIdx.x / FTILES;
    const int tile = blockIdx.x % FTILES;

    const float w0 = k_u[0], w1 = k_u[1];
    const float mk  = 0.5f * (w0 * w0 + w1 * w1);
    const float Mmu = SCALEQ * rsqrtf(mk);

    const float qk0 = qk_v[0], qk1 = qk_v[1], qk2 = qk_v[2], qk3 = qk_v[3], qk4 = qk_v[4];
    const float vv0 = v_v[0],  vv1 = v_v[1],  vv2 = v_v[2],  vv3 = v_v[3],  vv4 = v_v[4];

    for (int k = 0; k < SQ / 256; ++k) {
        const int j = tid + k * 256;
        const float* xr = x + (size_t)(b * SQ + j) * MDQ;
        const float x0 = xr[0], x1 = xr[1], x2 = xr[2], x3 = xr[3], x4 = xr[4];
        const float a  = x0*qk0 + x1*qk1 + x2*qk2 + x3*qk3 + x4*qk4;
        const float sv = x0*vv0 + x1*vv1 + x2*vv2 + x3*vv3 + x4*vv4;
        float sj, cj;
        __sincosf(freqs[j], &sj, &cj);
        const float mu = SCALEQ * a * rsqrtf(a * a * mk + EPSQ);
        sPQ[j] = make_float2(mu * cj, mu * sj);
        sCv[j] = sv;
    }

    const int row = tid & (FROWS - 1);
    const int sp  = tid / FROWS;
    const int i   = tile * FROWS + row;

    const float u00 = q_u[0], u01 = q_u[1], u10 = q_u[2], u11 = q_u[3];
    const float m0 = 0.5f * (u00 * u00 + u01 * u01);
    const float m1 = 0.5f * (u10 * u10 + u11 * u11);
    const float A0 = u00 * w0 + u01 * w1, B0 = u01 * w0 - u00 * w1;
    const float A1 = u10 * w0 + u11 * w1, B1 = u11 * w0 - u10 * w1;

    const float* xi = x + (size_t)(b * SQ + i) * MDQ;
    const float ai = xi[0]*qk0 + xi[1]*qk1 + xi[2]*qk2 + xi[3]*qk3 + xi[4]*qk4;
    float si, ci;
    __sincosf(freqs[i], &si, &ci);
    const float lam0 = SCALEQ * ai * rsqrtf(ai * ai * m0 + EPSQ);
    const float lam1 = SCALEQ * ai * rsqrtf(ai * ai * m1 + EPSQ);
    const float alr0 = lam0 * (A0 * ci - B0 * si) * ISQ2;
    const float ber0 = lam0 * (A0 * si + B0 * ci) * ISQ2;
    const float alr1 = lam1 * (A1 * ci - B1 * si) * ISQ2;
    const float ber1 = lam1 * (A1 * si + B1 * ci) * ISQ2;
    const float r0 = sqrtf(alr0 * alr0 + ber0 * ber0);
    const float r1 = sqrtf(alr1 * alr1 + ber1 * ber1);
    const float al0 = alr0 * L2E, be0 = ber0 * L2E, C0 = -r0 * Mmu * L2E;
    const float al1 = alr1 * L2E, be1 = ber1 * L2E, C1 = -r1 * Mmu * L2E;

    __syncthreads();

    const float2* __restrict__ pq  = sPQ + sp * FJSUB;
    const float*  __restrict__ cvp = sCv + sp * FJSUB;
    float l0 = 0.f, n0 = 0.f, l1 = 0.f, n1 = 0.f;
#pragma unroll 8
    for (int jj = 0; jj < FJSUB; ++jj) {
        const float2 v = pq[jj];
        const float cv = cvp[jj];
        const float s0 = fmaf(al0, v.x, fmaf(be0, v.y, C0));
        const float s1 = fmaf(al1, v.x, fmaf(be1, v.y, C1));
        const float e0 = fast_exp2(s0);
        const float e1 = fast_exp2(s1);
        l0 += e0; n0 = fmaf(e0, cv, n0);
        l1 += e1; n1 = fmaf(e1, cv, n1);
    }

    sRed[row][sp] = make_float4(l0, n0, l1, n1);
    __syncthreads();

    if (tid < FROWS) {
        float L0 = 0.f, N0 = 0.f, L1 = 0.f, N1 = 0.f;
#pragma unroll
        for (int s = 0; s < FSPLIT; ++s) {
            const float4 t = sRed[tid][s];
            L0 += t.x; N0 += t.y; L1 += t.z; N1 += t.w;
        }
        L0 = fmaxf(L0, 1e-30f);
        L1 = fmaxf(L1, 1e-30f);
        const float W0 = N0 / L0, W1 = N1 / L1;
        const float p0 = vproj_u[0], p1 = vproj_u[1];
        const float d0 = p0 * o_v[0] + p1 * o_v[1];
        const float d1 = p0 * o_v[2] + p1 * o_v[3];
        const float so = W0 * d0 + W1 * d1;

        const int ig = tile * FROWS + tid;
        float* orow = out + (size_t)(b * SQ + ig) * MDQ;
        orow[0] = so * o_u[0];
        orow[1] = so * o_u[1];
        orow[2] = so * o_u[2];
        orow[3] = so * o_u[3];
        orow[4] = so * o_u[4];
    }
}

extern "C" void kernel_launch(void* const* d_in, const int* in_sizes, int n_in,
                              void* d_out, int out_size, void* d_ws, size_t ws_size,
                              hipStream_t stream) {
    (void)in_sizes; (void)n_in; (void)out_size;
    const float* x       = (const float*)d_in[0];
    const float* freqs   = (const float*)d_in[1];
    const float* qk_v    = (const float*)d_in[2];
    const float* v_v     = (const float*)d_in[3];
    const float* o_v     = (const float*)d_in[4];
    const float* vproj_u = (const float*)d_in[5];
    const float* q_u     = (const float*)d_in[6];
    const float* k_u     = (const float*)d_in[7];
    const float* o_u     = (const float*)d_in[8];
    float* out = (float*)d_out;

    const size_t pqc_bytes = (size_t)BQ * SQ * sizeof(float4);   // 256 KB
    if (ws_size >= pqc_bytes) {
        float4* pqc = (float4*)d_ws;
        hipLaunchKernelGGL(ca_prep, dim3(BQ * SQ / 256), dim3(256), 0, stream,
                           x, freqs, qk_v, v_v, k_u, pqc);
        hipLaunchKernelGGL(ca_main, dim3(BQ * TILES), dim3(BLOCK), 0, stream,
                           x, freqs, qk_v, o_v, vproj_u, q_u, k_u, o_u, pqc, out);
    } else {
        hipLaunchKernelGGL(ca_fallback, dim3(BQ * FTILES), dim3(256), 0, stream,
                           x, freqs, qk_v, v_v, o_v, vproj_u, q_u, k_u, o_u, out);
    }
}